// Round 7
// baseline (65.217 us; speedup 1.0000x reference)
//
#include <hip/hip_runtime.h>
#include <math.h>

// Problem constants (fixed by the harness's setup_inputs)
#define HDIM 256
#define NDIM 64
#define LDIM 8192
#define LF   4097          // L/2 + 1
#define MDIM 4096          // L/2  (complex FFT size)
#define LOG2M 12
#define ILP  4             // l-values per thread in cauchy

typedef float v2f __attribute__((ext_vector_type(2)));

// ---------------------------------------------------------------------------
// Prep: per-(h,n) wave-uniform constants -> global (staged in d_out's front;
// ifft fully overwrites d_out afterwards).
//   ga = (w_r*dt, w_i*dt, v00_r, v00_i)
//   gb = (v01_r, v01_i, v10_r, v10_i)
//   gc = (v11_r, v11_i)
// ---------------------------------------------------------------------------
__global__ __launch_bounds__(256) void prep_kernel(
    const float* __restrict__ log_dt,
    const float* __restrict__ C_re, const float* __restrict__ C_im,
    const float* __restrict__ B_re, const float* __restrict__ B_im,
    const float* __restrict__ P_re, const float* __restrict__ P_im,
    const float* __restrict__ Q_re, const float* __restrict__ Q_im,
    const float* __restrict__ w_re, const float* __restrict__ w_im,
    float4* __restrict__ ga, float4* __restrict__ gb, float2* __restrict__ gc)
{
    const int idx = blockIdx.x * 256 + threadIdx.x;   // 64 blocks x 256
    if (idx >= HDIM * NDIM) return;
    const int h = idx >> 6;
    const float dt = expf(log_dt[h]);
    const float Br = B_re[idx], Bi = B_im[idx];
    const float Cr = C_re[idx], Ci = C_im[idx];
    const float Pr = P_re[idx], Pi = P_im[idx];
    const float Qr = Q_re[idx], Qi = Q_im[idx];
    ga[idx] = make_float4(w_re[idx] * dt, w_im[idx] * dt,
                          Cr*Br - Ci*Bi,  Cr*Bi + Ci*Br);   // C*B
    gb[idx] = make_float4(Cr*Pr - Ci*Pi,  Cr*Pi + Ci*Pr,    // C*P
                          Qr*Br - Qi*Bi,  Qr*Bi + Qi*Br);   // Q*B
    gc[idx] = make_float2(Qr*Pr - Qi*Pi,  Qr*Pi + Qi*Pr);   // Q*P
}

// ---------------------------------------------------------------------------
// Stage A: Cauchy + Woodbury -> k_f[h][l].
// R7: ILP=4 + one-group-ahead software prefetch of the SGPR constants
// (4 n-values per group; next group's s_loads issue before current group's
// ~900-cycle compute -> ~200-cycle scalar-load latency fully hidden).
//   U_ab = sum_n v_ab / D_n,  D = 2(1-omega) - w*dt*(1+omega)
//   k_f  = 2 dt U00 - (dt(1+w)U01)(2 dt U10) / (1 + dt(1+w)U11)
// ---------------------------------------------------------------------------
__global__ __launch_bounds__(256, 4) void cauchy_kernel(
    const float* __restrict__ log_dt,
    const float4* __restrict__ ga, const float4* __restrict__ gb,
    const float2* __restrict__ gc, float2* __restrict__ kf)
{
    const int h   = blockIdx.y;
    const int tid = threadIdx.x;
    const float dt = expf(log_dt[h]);
    const int hbase = h * NDIM;

    // Nyquist bin (l = 4096): omega=-1 -> D=4, (1+omega)=0 =>
    // k_f = 0.5*dt*sum_n v00[n]; Woodbury term vanishes.
    if (blockIdx.x == 0 && tid < 64) {
        const float4 a = ga[hbase + tid];
        float sr = a.z, si = a.w;
        #pragma unroll
        for (int off = 32; off > 0; off >>= 1) {
            sr += __shfl_xor(sr, off);
            si += __shfl_xor(si, off);
        }
        if (tid == 0)
            kf[h * LF + MDIM] = make_float2(0.5f * dt * sr, 0.5f * dt * si);
    }

    // per-thread l-values: l = blockIdx.x*1024 + k*256 + tid, k = 0..3 (<4096)
    const int lbase = blockIdx.x * (ILP * 256) + tid;

    v2f opw[ILP], td[ILP];
    #pragma unroll
    for (int k = 0; k < ILP; ++k) {
        const int l = lbase + k * 256;
        const float theta = (6.28318530717958647692f / (float)LDIM) * (float)l;
        float sn, cs;
        sincosf(theta, &sn, &cs);
        opw[k] = (v2f){1.f + cs, -sn};                 // 1 + omega
        td[k]  = (v2f){2.f * (1.f - cs), 2.f * sn};    // 2*(1 - omega)
    }

    v2f u00[ILP] = {}, u01[ILP] = {}, u10[ILP] = {}, u11[ILP] = {};

    // ---- software-pipelined constant stream: 16 groups of 4 n-values ----
    float4 a0[4], b0[4]; float2 c0[4];
    #pragma unroll
    for (int j = 0; j < 4; ++j) {
        a0[j] = ga[hbase + j]; b0[j] = gb[hbase + j]; c0[j] = gc[hbase + j];
    }

    #pragma unroll 1
    for (int g = 0; g < NDIM / 4; ++g) {
        // prefetch next group (wraps to 0 on the last iter - harmless)
        float4 a1[4], b1[4]; float2 c1[4];
        const int nb_ = hbase + (((g + 1) & 15) << 2);
        #pragma unroll
        for (int j = 0; j < 4; ++j) {
            a1[j] = ga[nb_ + j]; b1[j] = gb[nb_ + j]; c1[j] = gc[nb_ + j];
        }

        #pragma unroll
        for (int j = 0; j < 4; ++j) {
            const float4 a = a0[j];     // wr, wi, v00r, v00i
            const float4 b = b0[j];     // v01r, v01i, v10r, v10i
            const float2 c = c0[j];     // v11r, v11i
            const v2f wp  = (v2f){a.x, a.y};
            const v2f p00 = (v2f){a.z, a.w};
            const v2f p01 = (v2f){b.x, b.y};
            const v2f p10 = (v2f){b.z, b.w};
            const v2f p11 = (v2f){c.x, c.y};

            #pragma unroll
            for (int k = 0; k < ILP; ++k) {
                // D = td - wr*(or,oi) + wi*(oi,-or)  [D = td - w*(1+omega)]
                v2f D = td[k];
                asm("v_pk_fma_f32 %0, %1, %2, %0 op_sel:[0,0,0] op_sel_hi:[0,1,1] neg_lo:[1,0,0] neg_hi:[1,0,0]"
                    : "+v"(D) : "s"(wp), "v"(opw[k]));
                asm("v_pk_fma_f32 %0, %1, %2, %0 op_sel:[1,1,0] op_sel_hi:[1,0,1] neg_hi:[0,1,0]"
                    : "+v"(D) : "s"(wp), "v"(opw[k]));

                const float den = fmaf(D.x, D.x, D.y * D.y);
                const float r   = __builtin_amdgcn_rcpf(den);
                const v2f  rr   = (v2f){r, r};
                v2f m;                               // m = D*r ; 1/D = (m.x,-m.y)
                asm("v_pk_mul_f32 %0, %1, %2" : "=v"(m) : "v"(D), "v"(rr));

                // u += p * (m.x, -m.y)  (complex, two pk_fma per accumulator)
                asm("v_pk_fma_f32 %0, %1, %2, %0 op_sel:[0,0,0] op_sel_hi:[0,1,1] neg_hi:[0,1,0]"
                    : "+v"(u00[k]) : "s"(p00), "v"(m));
                asm("v_pk_fma_f32 %0, %1, %2, %0 op_sel:[1,1,0] op_sel_hi:[1,0,1]"
                    : "+v"(u00[k]) : "s"(p00), "v"(m));
                asm("v_pk_fma_f32 %0, %1, %2, %0 op_sel:[0,0,0] op_sel_hi:[0,1,1] neg_hi:[0,1,0]"
                    : "+v"(u01[k]) : "s"(p01), "v"(m));
                asm("v_pk_fma_f32 %0, %1, %2, %0 op_sel:[1,1,0] op_sel_hi:[1,0,1]"
                    : "+v"(u01[k]) : "s"(p01), "v"(m));
                asm("v_pk_fma_f32 %0, %1, %2, %0 op_sel:[0,0,0] op_sel_hi:[0,1,1] neg_hi:[0,1,0]"
                    : "+v"(u10[k]) : "s"(p10), "v"(m));
                asm("v_pk_fma_f32 %0, %1, %2, %0 op_sel:[1,1,0] op_sel_hi:[1,0,1]"
                    : "+v"(u10[k]) : "s"(p10), "v"(m));
                asm("v_pk_fma_f32 %0, %1, %2, %0 op_sel:[0,0,0] op_sel_hi:[0,1,1] neg_hi:[0,1,0]"
                    : "+v"(u11[k]) : "s"(p11), "v"(m));
                asm("v_pk_fma_f32 %0, %1, %2, %0 op_sel:[1,1,0] op_sel_hi:[1,0,1]"
                    : "+v"(u11[k]) : "s"(p11), "v"(m));
            }
        }

        #pragma unroll
        for (int j = 0; j < 4; ++j) { a0[j] = a1[j]; b0[j] = b1[j]; c0[j] = c1[j]; }
    }

    #pragma unroll
    for (int k = 0; k < ILP; ++k) {
        const int l = lbase + k * 256;
        const float two_dt = 2.f * dt;
        const float r00r = two_dt * u00[k].x, r00i = two_dt * u00[k].y;
        const float r10r = two_dt * u10[k].x, r10i = two_dt * u10[k].y;
        // r01 = dt*(1+omega)*U01 ; 1 + r11 = 1 + dt*(1+omega)*U11
        const float r01r = dt * (opw[k].x * u01[k].x - opw[k].y * u01[k].y);
        const float r01i = dt * (opw[k].x * u01[k].y + opw[k].y * u01[k].x);
        const float d_r  = 1.f + dt * (opw[k].x * u11[k].x - opw[k].y * u11[k].y);
        const float d_i  =       dt * (opw[k].x * u11[k].y + opw[k].y * u11[k].x);

        const float numr = r01r * r10r - r01i * r10i;
        const float numi = r01r * r10i + r01i * r10r;
        const float dd   = fmaf(d_r, d_r, d_i * d_i);
        const float rr2  = __builtin_amdgcn_rcpf(dd);
        const float cr = (numr * d_r + numi * d_i) * rr2;
        const float ci = (numi * d_r - numr * d_i) * rr2;

        kf[h * LF + l] = make_float2(r00r - cr, r00i - ci);
    }
}

// ---------------------------------------------------------------------------
// Stage B: inverse rfft via complex iFFT of size M = L/2. (unchanged, ~5 us)
// ---------------------------------------------------------------------------
__global__ __launch_bounds__(1024) void ifft_kernel(
    const float2* __restrict__ kf, float2* __restrict__ out2)
{
    __shared__ float2 S[MDIM];          // 32 KB

    const int h   = blockIdx.x;
    const int tid = threadIdx.x;
    const float2* K = kf + (size_t)h * LF;

    // ---- build Z (bit-reversed) from Hermitian half-spectrum ----
    for (int l = tid; l <= MDIM / 2; l += 1024) {
        const float2 Kl = K[l];
        const float2 Km = K[MDIM - l];
        const float Ar = 0.5f * (Kl.x + Km.x);
        const float Ai = 0.5f * (Kl.y - Km.y);
        const float Br = 0.5f * (Kl.x - Km.x);
        const float Bi = 0.5f * (Kl.y + Km.y);
        const float phi = (6.28318530717958647692f / (float)LDIM) * (float)l;
        float s, c;
        sincosf(phi, &s, &c);
        const float Or = c * Br - s * Bi;
        const float Oi = c * Bi + s * Br;
        const int bl = (int)(__brev((unsigned)l) >> (32 - LOG2M));
        S[bl] = make_float2(Ar - Oi, Ai + Or);
        if (l > 0 && l < MDIM / 2) {
            const int bm = (int)(__brev((unsigned)(MDIM - l)) >> (32 - LOG2M));
            S[bm] = make_float2(Ar + Oi, Or - Ai);
        }
    }

    // ---- 12 radix-2 DIT stages, inverse twiddles ----
    #pragma unroll
    for (int stage = 0; stage < LOG2M; ++stage) {
        const int half = 1 << stage;
        __syncthreads();
        #pragma unroll 2
        for (int t = tid; t < MDIM / 2; t += 1024) {
            const int pos = t & (half - 1);
            const int i0  = ((t & ~(half - 1)) << 1) | pos;
            const int i1  = i0 + half;
            const float ang = (3.14159265358979323846f / (float)half) * (float)pos;
            float s, c;
            sincosf(ang, &s, &c);
            const float2 a = S[i0];
            const float2 b = S[i1];
            const float tr = c * b.x - s * b.y;
            const float ti = c * b.y + s * b.x;
            S[i0] = make_float2(a.x + tr, a.y + ti);
            S[i1] = make_float2(a.x - tr, a.y - ti);
        }
    }
    __syncthreads();

    const float invM = 1.f / (float)MDIM;
    for (int n = tid; n < MDIM; n += 1024) {
        const float2 z = S[n];
        out2[(size_t)h * MDIM + n] = make_float2(z.x * invM, z.y * invM);
    }
}

extern "C" void kernel_launch(void* const* d_in, const int* in_sizes, int n_in,
                              void* d_out, int out_size, void* d_ws, size_t ws_size,
                              hipStream_t stream)
{
    const float* log_dt = (const float*)d_in[0];
    const float* C_re   = (const float*)d_in[1];
    const float* C_im   = (const float*)d_in[2];
    const float* B_re   = (const float*)d_in[3];
    const float* B_im   = (const float*)d_in[4];
    const float* P_re   = (const float*)d_in[5];
    const float* P_im   = (const float*)d_in[6];
    const float* Q_re   = (const float*)d_in[7];
    const float* Q_im   = (const float*)d_in[8];
    const float* w_re   = (const float*)d_in[9];
    const float* w_im   = (const float*)d_in[10];

    float2* kf = (float2*)d_ws;          // HDIM * LF * 8 B = 8.39 MB (in ws)

    // Stage constants in the FRONT of d_out (640 KB) — ifft_kernel fully
    // overwrites d_out afterwards, so this costs no workspace.
    char* scratch = (char*)d_out;
    float4* ga = (float4*)(scratch);                         // 256 KB
    float4* gb = (float4*)(scratch + 262144);                // 256 KB
    float2* gc = (float2*)(scratch + 524288);                // 128 KB
    float2* out2 = (float2*)d_out;

    prep_kernel<<<64, 256, 0, stream>>>(log_dt, C_re, C_im, B_re, B_im,
                                        P_re, P_im, Q_re, Q_im,
                                        w_re, w_im, ga, gb, gc);

    dim3 grid1(MDIM / (ILP * 256), HDIM);   // 4 x 256 = 1024 blocks, zero waste
    cauchy_kernel<<<grid1, 256, 0, stream>>>(log_dt, ga, gb, gc, kf);

    ifft_kernel<<<HDIM, 1024, 0, stream>>>(kf, out2);
}

// Round 8
// 61.812 us; speedup vs baseline: 1.0551x; 1.0551x over previous
//
#include <hip/hip_runtime.h>
#include <math.h>

// Problem constants (fixed by the harness's setup_inputs)
#define HDIM 256
#define NDIM 64
#define LDIM 8192
#define LF   4097          // L/2 + 1
#define MDIM 4096          // L/2  (complex FFT size)
#define LOG2M 12
#define ILP  4             // l-values per thread in cauchy

typedef float v2f __attribute__((ext_vector_type(2)));

__device__ __forceinline__ float rlane(float v, int n) {
    return __int_as_float(__builtin_amdgcn_readlane(__float_as_int(v), n));
}

// ---------------------------------------------------------------------------
// Stage A: Cauchy + Woodbury -> k_f[h][l].
// R8: constants live in VGPRs (each wave's lanes 0..63 hold pole i's ten
// constants; ~50-op prologue, duplicated per wave) and are broadcast per
// n-iteration with v_readlane (SGPR-indexed) straight into the VOP3P "s"
// operands. Zero LDS, zero s_load, zero prep kernel -> no constant-stream
// latency to hide at all.
//   U_ab = sum_n v_ab / D_n,  D = 2(1-omega) - w*dt*(1+omega)
//   k_f  = 2 dt U00 - (dt(1+w)U01)(2 dt U10) / (1 + dt(1+w)U11)
// ---------------------------------------------------------------------------
__global__ __launch_bounds__(256, 4) void cauchy_kernel(
    const float* __restrict__ log_dt,
    const float* __restrict__ C_re, const float* __restrict__ C_im,
    const float* __restrict__ B_re, const float* __restrict__ B_im,
    const float* __restrict__ P_re, const float* __restrict__ P_im,
    const float* __restrict__ Q_re, const float* __restrict__ Q_im,
    const float* __restrict__ w_re, const float* __restrict__ w_im,
    float2* __restrict__ kf)
{
    const int h    = blockIdx.y;
    const int tid  = threadIdx.x;
    const int lane = tid & 63;
    const float dt = expf(log_dt[h]);

    // ---- per-wave constant prologue: lane i holds pole i's constants ----
    const int idx = h * NDIM + lane;
    const float Br = B_re[idx], Bi = B_im[idx];
    const float Cr = C_re[idx], Ci = C_im[idx];
    const float Pr = P_re[idx], Pi = P_im[idx];
    const float Qr = Q_re[idx], Qi = Q_im[idx];
    const float wdr = w_re[idx] * dt, wdi = w_im[idx] * dt;
    const float v00r = Cr*Br - Ci*Bi, v00i = Cr*Bi + Ci*Br;   // C*B
    const float v01r = Cr*Pr - Ci*Pi, v01i = Cr*Pi + Ci*Pr;   // C*P
    const float v10r = Qr*Br - Qi*Bi, v10i = Qr*Bi + Qi*Br;   // Q*B
    const float v11r = Qr*Pr - Qi*Pi, v11i = Qr*Pi + Qi*Pr;   // Q*P

    // Nyquist bin (l = 4096): omega=-1 -> D=4, (1+omega)=0 =>
    // k_f = 0.5*dt*sum_n v00[n]; Woodbury term vanishes.
    if (blockIdx.x == 0 && tid < 64) {
        float sr = v00r, si = v00i;
        #pragma unroll
        for (int off = 32; off > 0; off >>= 1) {
            sr += __shfl_xor(sr, off);
            si += __shfl_xor(si, off);
        }
        if (tid == 0)
            kf[h * LF + MDIM] = make_float2(0.5f * dt * sr, 0.5f * dt * si);
    }

    // per-thread l-values: l = blockIdx.x*1024 + k*256 + tid, k = 0..3 (<4096)
    const int lbase = blockIdx.x * (ILP * 256) + tid;

    v2f opw[ILP], td[ILP];
    #pragma unroll
    for (int k = 0; k < ILP; ++k) {
        const int l = lbase + k * 256;
        const float theta = (6.28318530717958647692f / (float)LDIM) * (float)l;
        float sn, cs;
        sincosf(theta, &sn, &cs);
        opw[k] = (v2f){1.f + cs, -sn};                 // 1 + omega
        td[k]  = (v2f){2.f * (1.f - cs), 2.f * sn};    // 2*(1 - omega)
    }

    v2f u00[ILP] = {}, u01[ILP] = {}, u10[ILP] = {}, u11[ILP] = {};

    #pragma unroll 4
    for (int n = 0; n < NDIM; ++n) {
        // broadcast pole n's constants: 10 v_readlane, no memory, no latency
        const v2f wp  = (v2f){rlane(wdr,  n), rlane(wdi,  n)};
        const v2f p00 = (v2f){rlane(v00r, n), rlane(v00i, n)};
        const v2f p01 = (v2f){rlane(v01r, n), rlane(v01i, n)};
        const v2f p10 = (v2f){rlane(v10r, n), rlane(v10i, n)};
        const v2f p11 = (v2f){rlane(v11r, n), rlane(v11i, n)};

        #pragma unroll
        for (int k = 0; k < ILP; ++k) {
            // D = td - wr*(or,oi) + wi*(oi,-or)  [D = td - w*(1+omega)]
            v2f D = td[k];
            asm("v_pk_fma_f32 %0, %1, %2, %0 op_sel:[0,0,0] op_sel_hi:[0,1,1] neg_lo:[1,0,0] neg_hi:[1,0,0]"
                : "+v"(D) : "s"(wp), "v"(opw[k]));
            asm("v_pk_fma_f32 %0, %1, %2, %0 op_sel:[1,1,0] op_sel_hi:[1,0,1] neg_hi:[0,1,0]"
                : "+v"(D) : "s"(wp), "v"(opw[k]));

            const float den = fmaf(D.x, D.x, D.y * D.y);
            const float r   = __builtin_amdgcn_rcpf(den);
            const v2f  rr   = (v2f){r, r};
            v2f m;                               // m = D*r ; 1/D = (m.x,-m.y)
            asm("v_pk_mul_f32 %0, %1, %2" : "=v"(m) : "v"(D), "v"(rr));

            // u += p * (m.x, -m.y)  (complex, two pk_fma per accumulator)
            asm("v_pk_fma_f32 %0, %1, %2, %0 op_sel:[0,0,0] op_sel_hi:[0,1,1] neg_hi:[0,1,0]"
                : "+v"(u00[k]) : "s"(p00), "v"(m));
            asm("v_pk_fma_f32 %0, %1, %2, %0 op_sel:[1,1,0] op_sel_hi:[1,0,1]"
                : "+v"(u00[k]) : "s"(p00), "v"(m));
            asm("v_pk_fma_f32 %0, %1, %2, %0 op_sel:[0,0,0] op_sel_hi:[0,1,1] neg_hi:[0,1,0]"
                : "+v"(u01[k]) : "s"(p01), "v"(m));
            asm("v_pk_fma_f32 %0, %1, %2, %0 op_sel:[1,1,0] op_sel_hi:[1,0,1]"
                : "+v"(u01[k]) : "s"(p01), "v"(m));
            asm("v_pk_fma_f32 %0, %1, %2, %0 op_sel:[0,0,0] op_sel_hi:[0,1,1] neg_hi:[0,1,0]"
                : "+v"(u10[k]) : "s"(p10), "v"(m));
            asm("v_pk_fma_f32 %0, %1, %2, %0 op_sel:[1,1,0] op_sel_hi:[1,0,1]"
                : "+v"(u10[k]) : "s"(p10), "v"(m));
            asm("v_pk_fma_f32 %0, %1, %2, %0 op_sel:[0,0,0] op_sel_hi:[0,1,1] neg_hi:[0,1,0]"
                : "+v"(u11[k]) : "s"(p11), "v"(m));
            asm("v_pk_fma_f32 %0, %1, %2, %0 op_sel:[1,1,0] op_sel_hi:[1,0,1]"
                : "+v"(u11[k]) : "s"(p11), "v"(m));
        }
    }

    #pragma unroll
    for (int k = 0; k < ILP; ++k) {
        const int l = lbase + k * 256;
        const float two_dt = 2.f * dt;
        const float r00r = two_dt * u00[k].x, r00i = two_dt * u00[k].y;
        const float r10r = two_dt * u10[k].x, r10i = two_dt * u10[k].y;
        // r01 = dt*(1+omega)*U01 ; 1 + r11 = 1 + dt*(1+omega)*U11
        const float r01r = dt * (opw[k].x * u01[k].x - opw[k].y * u01[k].y);
        const float r01i = dt * (opw[k].x * u01[k].y + opw[k].y * u01[k].x);
        const float d_r  = 1.f + dt * (opw[k].x * u11[k].x - opw[k].y * u11[k].y);
        const float d_i  =       dt * (opw[k].x * u11[k].y + opw[k].y * u11[k].x);

        const float numr = r01r * r10r - r01i * r10i;
        const float numi = r01r * r10i + r01i * r10r;
        const float dd   = fmaf(d_r, d_r, d_i * d_i);
        const float rr2  = __builtin_amdgcn_rcpf(dd);
        const float cr = (numr * d_r + numi * d_i) * rr2;
        const float ci = (numi * d_r - numr * d_i) * rr2;

        kf[h * LF + l] = make_float2(r00r - cr, r00i - ci);
    }
}

// ---------------------------------------------------------------------------
// Stage B: inverse rfft via complex iFFT of size M = L/2. (unchanged, ~5 us)
// ---------------------------------------------------------------------------
__global__ __launch_bounds__(1024) void ifft_kernel(
    const float2* __restrict__ kf, float2* __restrict__ out2)
{
    __shared__ float2 S[MDIM];          // 32 KB

    const int h   = blockIdx.x;
    const int tid = threadIdx.x;
    const float2* K = kf + (size_t)h * LF;

    // ---- build Z (bit-reversed) from Hermitian half-spectrum ----
    for (int l = tid; l <= MDIM / 2; l += 1024) {
        const float2 Kl = K[l];
        const float2 Km = K[MDIM - l];
        const float Ar = 0.5f * (Kl.x + Km.x);
        const float Ai = 0.5f * (Kl.y - Km.y);
        const float Br = 0.5f * (Kl.x - Km.x);
        const float Bi = 0.5f * (Kl.y + Km.y);
        const float phi = (6.28318530717958647692f / (float)LDIM) * (float)l;
        float s, c;
        sincosf(phi, &s, &c);
        const float Or = c * Br - s * Bi;
        const float Oi = c * Bi + s * Br;
        const int bl = (int)(__brev((unsigned)l) >> (32 - LOG2M));
        S[bl] = make_float2(Ar - Oi, Ai + Or);
        if (l > 0 && l < MDIM / 2) {
            const int bm = (int)(__brev((unsigned)(MDIM - l)) >> (32 - LOG2M));
            S[bm] = make_float2(Ar + Oi, Or - Ai);
        }
    }

    // ---- 12 radix-2 DIT stages, inverse twiddles ----
    #pragma unroll
    for (int stage = 0; stage < LOG2M; ++stage) {
        const int half = 1 << stage;
        __syncthreads();
        #pragma unroll 2
        for (int t = tid; t < MDIM / 2; t += 1024) {
            const int pos = t & (half - 1);
            const int i0  = ((t & ~(half - 1)) << 1) | pos;
            const int i1  = i0 + half;
            const float ang = (3.14159265358979323846f / (float)half) * (float)pos;
            float s, c;
            sincosf(ang, &s, &c);
            const float2 a = S[i0];
            const float2 b = S[i1];
            const float tr = c * b.x - s * b.y;
            const float ti = c * b.y + s * b.x;
            S[i0] = make_float2(a.x + tr, a.y + ti);
            S[i1] = make_float2(a.x - tr, a.y - ti);
        }
    }
    __syncthreads();

    const float invM = 1.f / (float)MDIM;
    for (int n = tid; n < MDIM; n += 1024) {
        const float2 z = S[n];
        out2[(size_t)h * MDIM + n] = make_float2(z.x * invM, z.y * invM);
    }
}

extern "C" void kernel_launch(void* const* d_in, const int* in_sizes, int n_in,
                              void* d_out, int out_size, void* d_ws, size_t ws_size,
                              hipStream_t stream)
{
    const float* log_dt = (const float*)d_in[0];
    const float* C_re   = (const float*)d_in[1];
    const float* C_im   = (const float*)d_in[2];
    const float* B_re   = (const float*)d_in[3];
    const float* B_im   = (const float*)d_in[4];
    const float* P_re   = (const float*)d_in[5];
    const float* P_im   = (const float*)d_in[6];
    const float* Q_re   = (const float*)d_in[7];
    const float* Q_im   = (const float*)d_in[8];
    const float* w_re   = (const float*)d_in[9];
    const float* w_im   = (const float*)d_in[10];

    float2* kf = (float2*)d_ws;          // HDIM * LF * 8 B = 8.39 MB (in ws)
    float2* out2 = (float2*)d_out;

    dim3 grid1(MDIM / (ILP * 256), HDIM);   // 4 x 256 = 1024 blocks, zero waste
    cauchy_kernel<<<grid1, 256, 0, stream>>>(log_dt, C_re, C_im, B_re, B_im,
                                             P_re, P_im, Q_re, Q_im,
                                             w_re, w_im, kf);

    ifft_kernel<<<HDIM, 1024, 0, stream>>>(kf, out2);
}